// Round 7
// baseline (9571.426 us; speedup 1.0000x reference)
//
#include <hip/hip_runtime.h>
#include <stdint.h>
#include <math.h>

// Decoder: autoregressive GRU (B=128,H=512,T=256) -> LSTM (L=1024) -> FC (V=1024)
// fp32 I/O. Internal math fp32; GEMMs via MFMA 16x16x32 bf16 with split-bf16
// (hi/lo) weights AND activations, 3-pass MFMA.
//
// Round 11 (DIAGNOSTIC): two independent, separately-readable changes.
// (1) sync_probe kernel: 255 generations of the exact LSTM barrier topology
//     (256 blk x 512 thr, 32 group lines, arrive + vector poll) with ZERO
//     payload. Its duration (= dur_us - lstm_dur - gru_dur) measures the bare
//     grid-sync floor and discriminates sync-bound vs load-bound theories for
//     the stuck 27 us/step. Deliberate dur regression accepted this round.
// (2) LSTM weight-LDS bank-conflict fix: stride 1032/520 -> 1024/512 u16
//     (row term == 0 mod 32 banks) + XOR swizzle k ^= (row&7)<<3 on write and
//     read (bijective, short8-preserving). Readout: SQ_LDS_BANK_CONFLICT
//     2.17e8 -> expected <=5e7. GRU untouched (control for probe arithmetic).

typedef unsigned short u16;
typedef unsigned int u32;
typedef __attribute__((ext_vector_type(8))) short short8;   // 8 bf16 = 4 VGPR
typedef __attribute__((ext_vector_type(4))) float float4_;  // MFMA acc

#define MFMA(a, b, c) __builtin_amdgcn_mfma_f32_16x16x32_bf16((a), (b), (c), 0, 0, 0)

// System-coherent (LLC) 16B load, bypasses L1+L2; usable only after an owning wait.
#define SC_LOAD(dst, ptr) \
  asm volatile("global_load_dwordx4 %0, %1, off sc0 sc1" : "=v"(dst) : "v"(ptr) : "memory")
// s_waitcnt that also "owns" 8 loaded regs so consumers can't be hoisted above it.
#define WAIT8(n, a0,a1,a2,a3,a4,a5,a6,a7) \
  asm volatile("s_waitcnt vmcnt(" #n ")" \
    : "+v"(a0),"+v"(a1),"+v"(a2),"+v"(a3),"+v"(a4),"+v"(a5),"+v"(a6),"+v"(a7) :: "memory")
// Coherent 2B store (write-through to LLC, complete when vmcnt retires).
#define SC_STORE16(ptr, val) \
  asm volatile("global_store_short %0, %1, off sc0 sc1" :: "v"(ptr), "v"((u32)(val)) : "memory")

__device__ __forceinline__ float bf2f(u16 u) {
  union { u32 i; float f; } v; v.i = ((u32)u) << 16; return v.f;
}
__device__ __forceinline__ u16 f2bf(float f) {
  union { float f; u32 i; } v; v.f = f;
  u32 x = v.i;
  return (u16)((x + 0x7fffu + ((x >> 16) & 1u)) >> 16);  // RNE, finite inputs only
}
__device__ __forceinline__ void split2(float w, u16& h, u16& l) {
  h = f2bf(w); l = f2bf(w - bf2f(h));
}
__device__ __forceinline__ float sigm(float x) { return 1.0f / (1.0f + expf(-x)); }

__device__ __forceinline__ void frag_from_f32(const float* p, short8& hi, short8& lo) {
  short8 h, l;
#pragma unroll
  for (int j = 0; j < 8; ++j) {
    u16 a, b; split2(p[j], a, b);
    h[j] = (short)a; l[j] = (short)b;
  }
  hi = h; lo = l;
}

// System-scope acquire: s_waitcnt + buffer_inv (invalidate-only, preserves dirty).
__device__ __forceinline__ void cache_acquire() {
  __builtin_amdgcn_fence(__ATOMIC_ACQUIRE, "");
}

// --- Flat group barrier (no root) ------------------------------------------
__device__ __forceinline__ void bar_arrive(u32* grp) {
  asm volatile("s_waitcnt vmcnt(0)" ::: "memory");
  __syncthreads();
  if (threadIdx.x == 0) atomicAdd(grp, 1u);
}
template<int NG>
__device__ __forceinline__ void bar_wait_poll(u32* grpb, u32 target) {
  if (threadIdx.x < 64) {
    u32* p = grpb + (size_t)(threadIdx.x & (NG - 1)) * 32;
    while (true) {
      u32 v = __hip_atomic_load(p, __ATOMIC_RELAXED, __HIP_MEMORY_SCOPE_AGENT);
      if (__all((int)(v >= target))) break;
      __builtin_amdgcn_s_sleep(1);
    }
  }
  __syncthreads();
}

// ---------------------------------------------------------------------------
// DIAGNOSTIC: bare grid-sync floor, exact LSTM topology, zero payload.
// dur(sync_probe) / 255 = per-generation sync cost.
// ---------------------------------------------------------------------------
__global__ __launch_bounds__(512)
void sync_probe(u32* grpb, int gens) {
  u32* const mygrp = grpb + (size_t)(blockIdx.x >> 3) * 32;   // 32 groups of 8
  for (int g = 1; g <= gens; ++g) {
    bar_arrive(mygrp);
    bar_wait_poll<32>(grpb, (u32)g * 8u);
  }
}

// ---------------------------------------------------------------------------
// Kernel 1: persistent GRU chain. 128 blocks x 256 threads. UNCHANGED (control).
// ---------------------------------------------------------------------------
template<int C>
__global__ __launch_bounds__(256)
void gru_chain(const float* __restrict__ z,
               const float* __restrict__ Wih, const float* __restrict__ Whh,
               const float* __restrict__ bih, const float* __restrict__ bhh,
               u16* outu, u16* __restrict__ xpp, u32* grpb) {
  __shared__ __align__(16) u16 wh_lds[48 * 520];
  __shared__ __align__(16) u16 wl_lds[48 * 520];
  __shared__ float blds[32];

  const int tid = threadIdx.x;
  const int wg = blockIdx.x;
  const int grp = wg & 63;
  const int mhalf = wg >> 6;
  const int jb = grp * 8;
  u32* const mygrp = grpb + (size_t)(wg >> 3) * 32;   // 16 groups of 8, 128B apart

  for (int idx = tid; idx < 48 * 512; idx += 256) {
    int row = idx >> 9, k = idx & 511;
    int t3 = row >> 4, n = row & 15;
    int grow = t3 * 512 + jb + (n & 7);
    float w = ((n < 8) ? Wih : Whh)[(size_t)grow * 512 + k];
    u16 h, l; split2(w, h, l);
    wh_lds[row * 520 + k] = h;
    wl_lds[row * 520 + k] = l;
  }
  if (tid < 8) {
    blds[tid]      = bih[jb + tid] + bhh[jb + tid];
    blds[8 + tid]  = bih[512 + jb + tid] + bhh[512 + jb + tid];
    blds[16 + tid] = bih[1024 + jb + tid];
    blds[24 + tid] = bhh[1024 + jb + tid];
  }
  __syncthreads();

  const int lane = tid & 63, wv = tid >> 6;
  const int n16 = lane & 15, q = lane >> 4;
  const int j8 = n16 & 7;
  const int mrow = mhalf * 64 + wv * 16 + n16;
  const int orow0 = mhalf * 64 + wv * 16 + q * 4;
  const bool act = (n16 < 8);
  const int col = jb + j8;
  const int qo = q * 8;

  float x_own[4];

  // ---- step 1: x1 = GRU(x=0, h=z); A = z hi/lo (normal cached loads) ----
  {
    float4_ acc0 = {0.f, 0.f, 0.f, 0.f}, acc1 = acc0, acc2 = acc0;
    for (int ki = 0; ki < 16; ++ki) {
      const int ko = ki * 32 + qo;
      short8 ah, al;
      frag_from_f32(z + (size_t)mrow * 512 + ko, ah, al);
      short8 b0h = *(const short8*)(wh_lds + (0 * 16 + n16) * 520 + ko);
      short8 b1h = *(const short8*)(wh_lds + (1 * 16 + n16) * 520 + ko);
      short8 b2h = *(const short8*)(wh_lds + (2 * 16 + n16) * 520 + ko);
      short8 b0l = *(const short8*)(wl_lds + (0 * 16 + n16) * 520 + ko);
      short8 b1l = *(const short8*)(wl_lds + (1 * 16 + n16) * 520 + ko);
      short8 b2l = *(const short8*)(wl_lds + (2 * 16 + n16) * 520 + ko);
      acc0 = MFMA(ah, b0h, acc0); acc0 = MFMA(al, b0h, acc0); acc0 = MFMA(ah, b0l, acc0);
      acc1 = MFMA(ah, b1h, acc1); acc1 = MFMA(al, b1h, acc1); acc1 = MFMA(ah, b1l, acc1);
      acc2 = MFMA(ah, b2h, acc2); acc2 = MFMA(al, b2h, acc2); acc2 = MFMA(ah, b2l, acc2);
    }
    for (int reg = 0; reg < 4; ++reg) {
      float pr = __shfl_xor(acc0[reg], 8);
      float pz = __shfl_xor(acc1[reg], 8);
      float pn = __shfl_xor(acc2[reg], 8);
      float r  = sigm(pr + blds[j8]);
      float zg = sigm(pz + blds[8 + j8]);
      float nn = tanhf(blds[16 + j8] + r * (pn + blds[24 + j8]));
      float hv = act ? z[(size_t)(orow0 + reg) * 512 + col] : 0.f;
      float xn = (1.f - zg) * nn + zg * hv;
      x_own[reg] = xn;
      if (act) {
        size_t po = (size_t)(orow0 + reg) * 512 + col;
        u16 h, l; split2(xn, h, l);
        SC_STORE16(xpp + (size_t)1 * 131072 + po, h);           // slot 1 hi
        SC_STORE16(xpp + (size_t)1 * 131072 + 65536 + po, l);   // slot 1 lo
      }
    }
  }
  bar_arrive(mygrp);                          // gen 1
  if (act) {                                  // seq stores overlap the wait
    for (int reg = 0; reg < 4; ++reg) {
      float rl = fmaxf(x_own[reg], 0.f);
      u16 rh, rlo; split2(rl, rh, rlo);
      size_t so = ((size_t)(orow0 + reg) * 256 + 1) * 2048;
      outu[so + col] = rh;
      outu[so + 512 + col] = rlo;
    }
  }
  bar_wait_poll<16>(grpb, 8u);

  // ---- steps 2..255: A = x_{t-1} hi/lo ----
  for (int t = 2; t < 256; ++t) {
    if constexpr (C > 0) {
      if ((t & (C - 1)) == 0) cache_acquire();   // kill stale ring lines
    }
    const size_t sr = (C > 0) ? (size_t)((t - 1) & (C - 1)) : (size_t)((t - 1) & 1);
    const size_t sw = (C > 0) ? (size_t)(t & (C - 1))       : (size_t)(t & 1);
    const u16* xh = xpp + sr * 131072 + (size_t)mrow * 512;
    const u16* xl = xh + 65536;
    short8 bufh[16], bufl[16];
    if constexpr (C > 0) {
#pragma unroll
      for (int ki = 0; ki < 16; ++ki) {
        bufh[ki] = *(const short8*)(xh + ki * 32 + qo);
        bufl[ki] = *(const short8*)(xl + ki * 32 + qo);
      }
    } else {
#pragma unroll
      for (int ki = 0; ki < 16; ++ki) {
        SC_LOAD(bufh[ki], xh + ki * 32 + qo);
        SC_LOAD(bufl[ki], xl + ki * 32 + qo);
      }
      WAIT8(0, bufh[0], bufh[1], bufh[2], bufh[3], bufh[4], bufh[5], bufh[6], bufh[7]);
      WAIT8(0, bufh[8], bufh[9], bufh[10], bufh[11], bufh[12], bufh[13], bufh[14], bufh[15]);
      WAIT8(0, bufl[0], bufl[1], bufl[2], bufl[3], bufl[4], bufl[5], bufl[6], bufl[7]);
      WAIT8(0, bufl[8], bufl[9], bufl[10], bufl[11], bufl[12], bufl[13], bufl[14], bufl[15]);
    }

    float4_ acc0 = {0.f, 0.f, 0.f, 0.f}, acc1 = acc0, acc2 = acc0;
#pragma unroll
    for (int ki = 0; ki < 16; ++ki) {
      const int ko = ki * 32 + qo;
      short8 b0h = *(const short8*)(wh_lds + (0 * 16 + n16) * 520 + ko);
      short8 b1h = *(const short8*)(wh_lds + (1 * 16 + n16) * 520 + ko);
      short8 b2h = *(const short8*)(wh_lds + (2 * 16 + n16) * 520 + ko);
      short8 b0l = *(const short8*)(wl_lds + (0 * 16 + n16) * 520 + ko);
      short8 b1l = *(const short8*)(wl_lds + (1 * 16 + n16) * 520 + ko);
      short8 b2l = *(const short8*)(wl_lds + (2 * 16 + n16) * 520 + ko);
      acc0 = MFMA(bufh[ki], b0h, acc0); acc0 = MFMA(bufl[ki], b0h, acc0); acc0 = MFMA(bufh[ki], b0l, acc0);
      acc1 = MFMA(bufh[ki], b1h, acc1); acc1 = MFMA(bufl[ki], b1h, acc1); acc1 = MFMA(bufh[ki], b1l, acc1);
      acc2 = MFMA(bufh[ki], b2h, acc2); acc2 = MFMA(bufl[ki], b2h, acc2); acc2 = MFMA(bufh[ki], b2l, acc2);
    }
    // compute x_t and store the ring FIRST (the only data other blocks need)
    for (int reg = 0; reg < 4; ++reg) {
      float ar = acc0[reg], az = acc1[reg], an = acc2[reg];
      float pr = __shfl_xor(ar, 8), pz = __shfl_xor(az, 8), pn = __shfl_xor(an, 8);
      float r  = sigm(ar + pr + blds[j8]);
      float zg = sigm(az + pz + blds[8 + j8]);
      float nn = tanhf(an + blds[16 + j8] + r * (pn + blds[24 + j8]));
      float xn = (1.f - zg) * nn + zg * x_own[reg];
      x_own[reg] = xn;
      if (act) {
        size_t po = (size_t)(orow0 + reg) * 512 + col;
        u16 h, l; split2(xn, h, l);
        SC_STORE16(xpp + sw * 131072 + po, h);
        SC_STORE16(xpp + sw * 131072 + 65536 + po, l);
      }
    }
    if (t < 255) bar_arrive(mygrp);           // gen t
    if (act) {                                // seq stores overlap the wait
      for (int reg = 0; reg < 4; ++reg) {
        float rl = fmaxf(x_own[reg], 0.f);
        u16 rh, rlo; split2(rl, rh, rlo);
        size_t so = ((size_t)(orow0 + reg) * 256 + (size_t)t) * 2048;
        outu[so + col] = rh;
        outu[so + 512 + col] = rlo;
      }
    }
    if (t < 255) bar_wait_poll<16>(grpb, (u32)t * 8u);
  }
}

// ---------------------------------------------------------------------------
// Kernel 2: persistent LSTM chain with fused FC. 256 blocks x 512 threads.
// Round 11: weight-LDS stride 1024/512 u16 + XOR swizzle k^=(row&7)<<3 on
// write and read (bank-conflict fix). Barrier/ring structure = round 9.
// ---------------------------------------------------------------------------
template<int C>
__global__ __launch_bounds__(512)
void lstm_fc_chain(const float* __restrict__ Wih, const float* __restrict__ Whh,
                   const float* __restrict__ bih, const float* __restrict__ bhh,
                   const float* __restrict__ fcW, const float* __restrict__ fcb,
                   u16* __restrict__ hpp, u16* outu, float* outf, u32* grpb) {
  __shared__ __align__(16) u16 whh_hi[16 * 1024];
  __shared__ __align__(16) u16 whh_lo[16 * 1024];
  __shared__ __align__(16) u16 wih_hi[16 * 512];
  __shared__ __align__(16) u16 wih_lo[16 * 512];
  __shared__ float glds[128][17];
  __shared__ float pglds[2][16][4][16];
  __shared__ float bclds[16];
  __shared__ float fclds[16];

  const int tid = threadIdx.x;
  const int s = blockIdx.x;
  const int colbase = s * 4;
  const int vt = s & 63, bq = s >> 6;
  const int vbase = vt * 16;
  u32* const mygrp = grpb + (size_t)(s >> 3) * 32;   // 32 groups of 8, 128B apart

  for (int idx = tid; idx < 16 * 1024; idx += 512) {
    int row = idx >> 10, k = idx & 1023;
    int gate = row >> 2, cc = row & 3;
    float w = Whh[(size_t)(gate * 1024 + colbase + cc) * 1024 + k];
    u16 h, l; split2(w, h, l);
    int ks = k ^ ((row & 7) << 3);            // bank swizzle (bijective per row)
    whh_hi[row * 1024 + ks] = h;
    whh_lo[row * 1024 + ks] = l;
  }
  for (int idx = tid; idx < 16 * 512; idx += 512) {
    int row = idx >> 9, k = idx & 511;
    int gate = row >> 2, cc = row & 3;
    float w = Wih[(size_t)(gate * 1024 + colbase + cc) * 512 + k];
    u16 h, l; split2(w, h, l);
    int ks = k ^ ((row & 7) << 3);
    wih_hi[row * 512 + ks] = h;
    wih_lo[row * 512 + ks] = l;
  }
  if (tid < 16) {
    int gate = tid >> 2, cc = tid & 3;
    int wcol = gate * 1024 + colbase + cc;
    bclds[tid] = bih[wcol] + bhh[wcol];
    fclds[tid] = fcb[vbase + tid];
  }
  __syncthreads();

  const int lane = tid & 63, wv = tid >> 6;
  const int n16 = lane & 15, q = lane >> 4;
  const int qo = q * 8;
  const int nsw = (n16 & 7) << 3;             // per-lane read swizzle
  const int arow = wv * 16 + n16;
  const int myrow = tid >> 2, mycol = tid & 3;
  const int fmt = wv & 1, fkq = wv >> 1;
  const int frow = bq * 32 + fmt * 16 + n16;
  const int fkbase = fkq * 256;

  short8 brh[8], brl[8];
  for (int i = 0; i < 8; ++i)
    frag_from_f32(fcW + (size_t)(vbase + n16) * 1024 + fkbase + i * 32 + qo,
                  brh[i], brl[i]);

  float c = 0.f;

  // t = 0: preacts are just biases; write h_0 into slot 0, arrive gen 1.
  {
    float pi = bclds[mycol], pg = bclds[8 + mycol], po = bclds[12 + mycol];
    c = sigm(pi) * tanhf(pg);
    float h = sigm(po) * tanhf(c);
    size_t off = (size_t)myrow * 1024 + colbase + mycol;
    u16 hh, hl; split2(h, hh, hl);
    SC_STORE16(hpp + off, hh);
    SC_STORE16(hpp + 131072 + off, hl);
  }
  bar_arrive(mygrp);   // gen 1

  for (int t = 1; t < 256; ++t) {
    const size_t sr = (C > 0) ? (size_t)((t - 1) & (C - 1)) : (size_t)((t - 1) & 1);
    const size_t sw = (C > 0) ? (size_t)(t & (C - 1))       : (size_t)(t & 1);

    // ---- input part FIRST (depends only on seq, not on h): hides the wait ----
    float4_ accI = {0.f, 0.f, 0.f, 0.f};
    {
      const u16* sq = outu + ((size_t)arow * 256 + t) * 2048;
      for (int ki = 0; ki < 16; ++ki) {
        const int ko = ki * 32 + qo;
        const int kw = ko ^ nsw;
        short8 sh = *(const short8*)(sq + ko);
        short8 sl = *(const short8*)(sq + 512 + ko);
        short8 bh = *(const short8*)(wih_hi + n16 * 512 + kw);
        short8 bl = *(const short8*)(wih_lo + n16 * 512 + kw);
        accI = MFMA(sh, bh, accI); accI = MFMA(sl, bh, accI); accI = MFMA(sh, bl, accI);
      }
    }

    if constexpr (C > 0) {
      if ((t & (C - 1)) == 0) cache_acquire();   // kill stale ring lines
    }
    bar_wait_poll<32>(grpb, (u32)t * 8u);        // h_{t-1} now visible

    const u16* ph = hpp + sr * 262144 + (size_t)arow * 1024;
    const u16* pl = ph + 131072;

    // recurrent part, K=1024: 4 chunks of 8 ki; two independent acc chains
    float4_ accR0 = {0.f, 0.f, 0.f, 0.f}, accR1 = accR0;
    {
      short8 hb[2][8], lb[2][8];
      if constexpr (C > 0) {
#pragma unroll
        for (int j = 0; j < 8; ++j) {
          hb[0][j] = *(const short8*)(ph + j * 32 + qo);
          lb[0][j] = *(const short8*)(pl + j * 32 + qo);
        }
#pragma unroll
        for (int ch = 0; ch < 4; ++ch) {
          const int cur = ch & 1, nxt = cur ^ 1;
          if (ch < 3) {
#pragma unroll
            for (int j = 0; j < 8; ++j) {
              hb[nxt][j] = *(const short8*)(ph + ((ch + 1) * 8 + j) * 32 + qo);
              lb[nxt][j] = *(const short8*)(pl + ((ch + 1) * 8 + j) * 32 + qo);
            }
          }
          float4_& accR = (ch < 2) ? accR0 : accR1;
#pragma unroll
          for (int j = 0; j < 8; ++j) {
            const int ko = (ch * 8 + j) * 32 + qo;
            const int kw = ko ^ nsw;
            short8 bh = *(const short8*)(whh_hi + n16 * 1024 + kw);
            short8 bl = *(const short8*)(whh_lo + n16 * 1024 + kw);
            accR = MFMA(hb[cur][j], bh, accR);
            accR = MFMA(lb[cur][j], bh, accR);
            accR = MFMA(hb[cur][j], bl, accR);
          }
        }
      } else {
#pragma unroll
        for (int j = 0; j < 8; ++j) {
          SC_LOAD(hb[0][j], ph + j * 32 + qo);
          SC_LOAD(lb[0][j], pl + j * 32 + qo);
        }
#pragma unroll
        for (int ch = 0; ch < 4; ++ch) {
          const int cur = ch & 1, nxt = cur ^ 1;
          if (ch < 3) {
#pragma unroll
            for (int j = 0; j < 8; ++j) {
              SC_LOAD(hb[nxt][j], ph + ((ch + 1) * 8 + j) * 32 + qo);
              SC_LOAD(lb[nxt][j], pl + ((ch + 1) * 8 + j) * 32 + qo);
            }
            WAIT8(16, hb[cur][0], hb[cur][1], hb[cur][2], hb[cur][3],
                      hb[cur][4], hb[cur][5], hb[cur][6], hb[cur][7]);
            WAIT8(16, lb[cur][0], lb[cur][1], lb[cur][2], lb[cur][3],
                      lb[cur][4], lb[cur][5], lb[cur][6], lb[cur][7]);
          } else {
            WAIT8(0, hb[cur][0], hb[cur][1], hb[cur][2], hb[cur][3],
                     hb[cur][4], hb[cur][5], hb[cur][6], hb[cur][7]);
            WAIT8(0, lb[cur][0], lb[cur][1], lb[cur][2], lb[cur][3],
                     lb[cur][4], lb[cur][5], lb[cur][6], lb[cur][7]);
          }
          float4_& accR = (ch < 2) ? accR0 : accR1;
#pragma unroll
          for (int j = 0; j < 8; ++j) {
            const int ko = (ch * 8 + j) * 32 + qo;
            const int kw = ko ^ nsw;
            short8 bh = *(const short8*)(whh_hi + n16 * 1024 + kw);
            short8 bl = *(const short8*)(whh_lo + n16 * 1024 + kw);
            accR = MFMA(hb[cur][j], bh, accR);
            accR = MFMA(lb[cur][j], bh, accR);
            accR = MFMA(hb[cur][j], bl, accR);
          }
        }
      }
    }
    for (int reg = 0; reg < 4; ++reg)
      glds[wv * 16 + q * 4 + reg][n16] = accI[reg] + accR0[reg] + accR1[reg];
    __syncthreads();
    {
      float pi = glds[myrow][mycol]      + bclds[mycol];
      float pf = glds[myrow][4 + mycol]  + bclds[4 + mycol];
      float pg = glds[myrow][8 + mycol]  + bclds[8 + mycol];
      float po = glds[myrow][12 + mycol] + bclds[12 + mycol];
      c = sigm(pf) * c + sigm(pi) * tanhf(pg);
      float h = sigm(po) * tanhf(c);
      size_t off = (size_t)myrow * 1024 + colbase + mycol;
      u16 hh, hl; split2(h, hh, hl);
      SC_STORE16(hpp + sw * 262144 + off, hh);
      SC_STORE16(hpp + sw * 262144 + 131072 + off, hl);
    }

    // ring mode: arrive NOW -- the FC below is not consumed by other blocks.
    if constexpr (C > 0) bar_arrive(mygrp);   // gen t+1

    // fused FC: logits_{t-1} from h_{t-1} (slot sr)
    {
      const u16* fh = hpp + sr * 262144 + (size_t)frow * 1024 + fkbase;
      const u16* fl = fh + 131072;
      short8 fhb[8], flb[8];
      if constexpr (C > 0) {
#pragma unroll
        for (int i = 0; i < 8; ++i) {
          fhb[i] = *(const short8*)(fh + i * 32 + qo);
          flb[i] = *(const short8*)(fl + i * 32 + qo);
        }
      } else {
#pragma unroll
        for (int i = 0; i < 8; ++i) {
          SC_LOAD(fhb[i], fh + i * 32 + qo);
          SC_LOAD(flb[i], fl + i * 32 + qo);
        }
        WAIT8(0, fhb[0], fhb[1], fhb[2], fhb[3], fhb[4], fhb[5], fhb[6], fhb[7]);
        WAIT8(0, flb[0], flb[1], flb[2], flb[3], flb[4], flb[5], flb[6], flb[7]);
      }
      float4_ lacc = {0.f, 0.f, 0.f, 0.f};
#pragma unroll
      for (int i = 0; i < 8; ++i) {
        lacc = MFMA(fhb[i], brh[i], lacc);
        lacc = MFMA(flb[i], brh[i], lacc);
        lacc = MFMA(fhb[i], brl[i], lacc);
      }
      for (int reg = 0; reg < 4; ++reg)
        pglds[fmt][q * 4 + reg][fkq][n16] = lacc[reg];
      __syncthreads();
      int trow = tid >> 4, tcol = tid & 15;
      float lsum = pglds[trow >> 4][trow & 15][0][tcol] + pglds[trow >> 4][trow & 15][1][tcol] +
                   pglds[trow >> 4][trow & 15][2][tcol] + pglds[trow >> 4][trow & 15][3][tcol] +
                   fclds[tcol];
      outf[((size_t)(bq * 32 + trow) * 256 + (t - 1)) * 1024 + vbase + tcol] = lsum;
    }

    if constexpr (C == 0) bar_arrive(mygrp);  // legacy order for 2-slot mode
  }

  // epilogue: logits_255 from h_255
  {
    bar_wait_poll<32>(grpb, 256u * 8u);
    if constexpr (C > 0) cache_acquire();
    const size_t sl = (C > 0) ? (size_t)(255 & (C - 1)) : (size_t)1;
    const u16* fh = hpp + sl * 262144 + (size_t)frow * 1024 + fkbase;
    const u16* fl = fh + 131072;
    short8 fhb[8], flb[8];
    if constexpr (C > 0) {
#pragma unroll
      for (int i = 0; i < 8; ++i) {
        fhb[i] = *(const short8*)(fh + i * 32 + qo);
        flb[i] = *(const short8*)(fl + i * 32 + qo);
      }
    } else {
#pragma unroll
      for (int i = 0; i < 8; ++i) {
        SC_LOAD(fhb[i], fh + i * 32 + qo);
        SC_LOAD(flb[i], fl + i * 32 + qo);
      }
      WAIT8(0, fhb[0], fhb[1], fhb[2], fhb[3], fhb[4], fhb[5], fhb[6], fhb[7]);
      WAIT8(0, flb[0], flb[1], flb[2], flb[3], flb[4], flb[5], flb[6], flb[7]);
    }
    float4_ lacc = {0.f, 0.f, 0.f, 0.f};
#pragma unroll
    for (int i = 0; i < 8; ++i) {
      lacc = MFMA(fhb[i], brh[i], lacc);
      lacc = MFMA(flb[i], brh[i], lacc);
      lacc = MFMA(fhb[i], brl[i], lacc);
    }
    for (int reg = 0; reg < 4; ++reg)
      pglds[fmt][q * 4 + reg][fkq][n16] = lacc[reg];
    __syncthreads();
    int trow = tid >> 4, tcol = tid & 15;
    float lsum = pglds[trow >> 4][trow & 15][0][tcol] + pglds[trow >> 4][trow & 15][1][tcol] +
                 pglds[trow >> 4][trow & 15][2][tcol] + pglds[trow >> 4][trow & 15][3][tcol] +
                 fclds[tcol];
    outf[((size_t)(bq * 32 + trow) * 256 + 255) * 1024 + vbase + tcol] = lsum;
  }
}

// ---------------------------------------------------------------------------
extern "C" void kernel_launch(void* const* d_in, const int* in_sizes, int n_in,
                              void* d_out, int out_size, void* d_ws, size_t ws_size,
                              hipStream_t stream) {
  (void)in_sizes; (void)n_in; (void)out_size;
  const float* z    = (const float*)d_in[0];
  const float* gWih = (const float*)d_in[2];
  const float* gWhh = (const float*)d_in[3];
  const float* gbih = (const float*)d_in[4];
  const float* gbhh = (const float*)d_in[5];
  const float* lWih = (const float*)d_in[6];
  const float* lWhh = (const float*)d_in[7];
  const float* lbih = (const float*)d_in[8];
  const float* lbhh = (const float*)d_in[9];
  const float* fcW  = (const float*)d_in[10];
  const float* fcb  = (const float*)d_in[11];

  const size_t XS = 262144;   // x slot bytes (2 planes x 128x512 bf16)
  const size_t HS = 524288;   // h slot bytes (2 planes x 128x1024 bf16)
  const size_t BAR = 16384;   // barrier region: LSTM + GRU + probe group lines

  char* w = (char*)d_ws;
  u32* grpL = (u32*)(w + 512);    // 32 x 128B LSTM group lines
  u32* grpG = (u32*)(w + 4608);   // 16 x 128B GRU group lines
  u32* grpP = (u32*)(w + 8192);   // 32 x 128B probe group lines

  hipMemsetAsync(d_ws, 0, BAR, stream);   // zero all barrier counters

  // DIAGNOSTIC: bare sync floor for LSTM topology (duration read via
  // dur_us - lstm_dur - gru_dur). 255 generations, zero payload.
  sync_probe<<<256, 512, 0, stream>>>(grpP, 255);

#define LAUNCH(CG, CL, XSLOTS)                                                     \
  do {                                                                             \
    u16* xpp = (u16*)(w + BAR);                                                    \
    u16* hpp = (u16*)(w + BAR + (size_t)(XSLOTS) * XS);                            \
    gru_chain<CG><<<128, 256, 0, stream>>>(z, gWih, gWhh, gbih, gbhh,              \
                                           (u16*)d_out, xpp, grpG);                \
    lstm_fc_chain<CL><<<256, 512, 0, stream>>>(lWih, lWhh, lbih, lbhh, fcW, fcb,   \
                                               hpp, (u16*)d_out, (float*)d_out,    \
                                               grpL);                              \
  } while (0)

  if      (ws_size >= BAR + 64 * XS + 128 * HS) LAUNCH(64, 128, 64);  // 83.9 MB
  else if (ws_size >= BAR + 32 * XS +  64 * HS) LAUNCH(32,  64, 32);  // 41.9 MB
  else if (ws_size >= BAR + 16 * XS +  32 * HS) LAUNCH(16,  32, 16);  // 21.0 MB
  else if (ws_size >= BAR +  8 * XS +  16 * HS) LAUNCH( 8,  16,  8);  // 10.5 MB
  else if (ws_size >= BAR +  2 * XS +   8 * HS) LAUNCH( 0,   8,  2);  //  4.7 MB (guaranteed)
  else if (ws_size >= BAR +  2 * XS +   2 * HS) LAUNCH( 0,   0,  2);  //  1.5 MB fallback
  else return;

#undef LAUNCH
}

// Round 8
// 8518.732 us; speedup vs baseline: 1.1236x; 1.1236x over previous
//
#include <hip/hip_runtime.h>
#include <stdint.h>
#include <math.h>

// Decoder: autoregressive GRU (B=128,H=512,T=256) -> LSTM (L=1024) -> FC (V=1024)
// fp32 I/O. Internal math fp32; GEMMs via MFMA 16x16x32 bf16 with split-bf16
// (hi/lo) weights AND activations, 3-pass MFMA.
//
// Round 12: L2-CHANNEL DE-ALIASING. Round-11 probe measured bare grid-sync at
// ~2.1 us/gen (sync theories dead) and showed SQ_LDS_BANK_CONFLICT invariant
// under the weight swizzle (weight-LDS reads not the cost). Remaining model:
// power-of-2 row strides alias the broadcast reads onto 1-2 of 16 L2 channels
// (h rows 2KB apart -> channel bits advance by 8 -> 2 channels; seq t-blocks
// 4KB-aligned -> all 16 rows of a wave on channel 0). Fix is pure layout:
// (a) h ring and x ring stored as contiguous 16-row x 32-col tiles (1KB) so a
//     wave load covers one contiguous 1KB tile (channels cycle);
// (b) seq rotated 256B per row inside each (row,t) 4KB block, writer+reader.
// No arithmetic change -> absmax bit-identical. sync_probe removed.

typedef unsigned short u16;
typedef unsigned int u32;
typedef __attribute__((ext_vector_type(8))) short short8;   // 8 bf16 = 4 VGPR
typedef __attribute__((ext_vector_type(4))) float float4_;  // MFMA acc

#define MFMA(a, b, c) __builtin_amdgcn_mfma_f32_16x16x32_bf16((a), (b), (c), 0, 0, 0)

// System-coherent (LLC) 16B load, bypasses L1+L2; usable only after an owning wait.
#define SC_LOAD(dst, ptr) \
  asm volatile("global_load_dwordx4 %0, %1, off sc0 sc1" : "=v"(dst) : "v"(ptr) : "memory")
// s_waitcnt that also "owns" 8 loaded regs so consumers can't be hoisted above it.
#define WAIT8(n, a0,a1,a2,a3,a4,a5,a6,a7) \
  asm volatile("s_waitcnt vmcnt(" #n ")" \
    : "+v"(a0),"+v"(a1),"+v"(a2),"+v"(a3),"+v"(a4),"+v"(a5),"+v"(a6),"+v"(a7) :: "memory")
// Coherent 2B store (write-through to LLC, complete when vmcnt retires).
#define SC_STORE16(ptr, val) \
  asm volatile("global_store_short %0, %1, off sc0 sc1" :: "v"(ptr), "v"((u32)(val)) : "memory")

__device__ __forceinline__ float bf2f(u16 u) {
  union { u32 i; float f; } v; v.i = ((u32)u) << 16; return v.f;
}
__device__ __forceinline__ u16 f2bf(float f) {
  union { float f; u32 i; } v; v.f = f;
  u32 x = v.i;
  return (u16)((x + 0x7fffu + ((x >> 16) & 1u)) >> 16);  // RNE, finite inputs only
}
__device__ __forceinline__ void split2(float w, u16& h, u16& l) {
  h = f2bf(w); l = f2bf(w - bf2f(h));
}
__device__ __forceinline__ float sigm(float x) { return 1.0f / (1.0f + expf(-x)); }

__device__ __forceinline__ void frag_from_f32(const float* p, short8& hi, short8& lo) {
  short8 h, l;
#pragma unroll
  for (int j = 0; j < 8; ++j) {
    u16 a, b; split2(p[j], a, b);
    h[j] = (short)a; l[j] = (short)b;
  }
  hi = h; lo = l;
}

// System-scope acquire: s_waitcnt + buffer_inv (invalidate-only, preserves dirty).
__device__ __forceinline__ void cache_acquire() {
  __builtin_amdgcn_fence(__ATOMIC_ACQUIRE, "");
}

// --- Flat group barrier (no root) ------------------------------------------
__device__ __forceinline__ void bar_arrive(u32* grp) {
  asm volatile("s_waitcnt vmcnt(0)" ::: "memory");
  __syncthreads();
  if (threadIdx.x == 0) atomicAdd(grp, 1u);
}
template<int NG>
__device__ __forceinline__ void bar_wait_poll(u32* grpb, u32 target) {
  if (threadIdx.x < 64) {
    u32* p = grpb + (size_t)(threadIdx.x & (NG - 1)) * 32;
    while (true) {
      u32 v = __hip_atomic_load(p, __ATOMIC_RELAXED, __HIP_MEMORY_SCOPE_AGENT);
      if (__all((int)(v >= target))) break;
      __builtin_amdgcn_s_sleep(1);
    }
  }
  __syncthreads();
}

// Tile-layout offset helpers (u16 units).
// x slot plane: 128 rows x 512 cols -> tiles (r>>4, k>>5), tile = 16x32 = 512 u16.
__device__ __forceinline__ size_t xoff(int r, int k) {
  return ((size_t)((r >> 4) * 16 + (k >> 5))) * 512 + (r & 15) * 32 + (k & 31);
}
// h slot plane: 128 rows x 1024 cols -> tiles (r>>4, k>>5), tile = 16x32 = 512 u16.
__device__ __forceinline__ size_t hoff(int r, int k) {
  return ((size_t)((r >> 4) * 32 + (k >> 5))) * 512 + (r & 15) * 32 + (k & 31);
}

// ---------------------------------------------------------------------------
// Kernel 1: persistent GRU chain. 128 blocks x 256 threads. 16 groups of 8.
// C==0: 2-slot sc0sc1 mode. C>0 (power of 2): C-slot ring, plain cached
// consumer loads + acquire fence every C steps.
// x slot layout: TILED (see xoff). seq: rotated 256B/row inside 4KB blocks.
// ---------------------------------------------------------------------------
template<int C>
__global__ __launch_bounds__(256)
void gru_chain(const float* __restrict__ z,
               const float* __restrict__ Wih, const float* __restrict__ Whh,
               const float* __restrict__ bih, const float* __restrict__ bhh,
               u16* outu, u16* __restrict__ xpp, u32* grpb) {
  __shared__ __align__(16) u16 wh_lds[48 * 520];
  __shared__ __align__(16) u16 wl_lds[48 * 520];
  __shared__ float blds[32];

  const int tid = threadIdx.x;
  const int wg = blockIdx.x;
  const int grp = wg & 63;
  const int mhalf = wg >> 6;
  const int jb = grp * 8;
  u32* const mygrp = grpb + (size_t)(wg >> 3) * 32;   // 16 groups of 8, 128B apart

  for (int idx = tid; idx < 48 * 512; idx += 256) {
    int row = idx >> 9, k = idx & 511;
    int t3 = row >> 4, n = row & 15;
    int grow = t3 * 512 + jb + (n & 7);
    float w = ((n < 8) ? Wih : Whh)[(size_t)grow * 512 + k];
    u16 h, l; split2(w, h, l);
    wh_lds[row * 520 + k] = h;
    wl_lds[row * 520 + k] = l;
  }
  if (tid < 8) {
    blds[tid]      = bih[jb + tid] + bhh[jb + tid];
    blds[8 + tid]  = bih[512 + jb + tid] + bhh[512 + jb + tid];
    blds[16 + tid] = bih[1024 + jb + tid];
    blds[24 + tid] = bhh[1024 + jb + tid];
  }
  __syncthreads();

  const int lane = tid & 63, wv = tid >> 6;
  const int n16 = lane & 15, q = lane >> 4;
  const int j8 = n16 & 7;
  const int mrow = mhalf * 64 + wv * 16 + n16;
  const int orow0 = mhalf * 64 + wv * 16 + q * 4;
  const bool act = (n16 < 8);
  const int col = jb + j8;
  const int qo = q * 8;
  const int xg = mhalf * 4 + wv;          // mrow >> 4 (tile row-group)

  float x_own[4];

  // ---- step 1: x1 = GRU(x=0, h=z); A = z hi/lo (normal cached loads) ----
  {
    float4_ acc0 = {0.f, 0.f, 0.f, 0.f}, acc1 = acc0, acc2 = acc0;
    for (int ki = 0; ki < 16; ++ki) {
      const int ko = ki * 32 + qo;
      short8 ah, al;
      frag_from_f32(z + (size_t)mrow * 512 + ko, ah, al);
      short8 b0h = *(const short8*)(wh_lds + (0 * 16 + n16) * 520 + ko);
      short8 b1h = *(const short8*)(wh_lds + (1 * 16 + n16) * 520 + ko);
      short8 b2h = *(const short8*)(wh_lds + (2 * 16 + n16) * 520 + ko);
      short8 b0l = *(const short8*)(wl_lds + (0 * 16 + n16) * 520 + ko);
      short8 b1l = *(const short8*)(wl_lds + (1 * 16 + n16) * 520 + ko);
      short8 b2l = *(const short8*)(wl_lds + (2 * 16 + n16) * 520 + ko);
      acc0 = MFMA(ah, b0h, acc0); acc0 = MFMA(al, b0h, acc0); acc0 = MFMA(ah, b0l, acc0);
      acc1 = MFMA(ah, b1h, acc1); acc1 = MFMA(al, b1h, acc1); acc1 = MFMA(ah, b1l, acc1);
      acc2 = MFMA(ah, b2h, acc2); acc2 = MFMA(al, b2h, acc2); acc2 = MFMA(ah, b2l, acc2);
    }
    for (int reg = 0; reg < 4; ++reg) {
      float pr = __shfl_xor(acc0[reg], 8);
      float pz = __shfl_xor(acc1[reg], 8);
      float pn = __shfl_xor(acc2[reg], 8);
      float r  = sigm(pr + blds[j8]);
      float zg = sigm(pz + blds[8 + j8]);
      float nn = tanhf(blds[16 + j8] + r * (pn + blds[24 + j8]));
      float hv = act ? z[(size_t)(orow0 + reg) * 512 + col] : 0.f;
      float xn = (1.f - zg) * nn + zg * hv;
      x_own[reg] = xn;
      if (act) {
        size_t po = xoff(orow0 + reg, col);
        u16 h, l; split2(xn, h, l);
        SC_STORE16(xpp + (size_t)1 * 131072 + po, h);           // slot 1 hi
        SC_STORE16(xpp + (size_t)1 * 131072 + 65536 + po, l);   // slot 1 lo
      }
    }
  }
  bar_arrive(mygrp);                          // gen 1
  if (act) {                                  // seq stores overlap the wait
    for (int reg = 0; reg < 4; ++reg) {
      int row = orow0 + reg;
      float rl = fmaxf(x_own[reg], 0.f);
      u16 rh, rlo; split2(rl, rh, rlo);
      size_t B = ((size_t)row * 256 + 1) * 2048;
      u32 rot = (u32)(row & 15) * 128;
      outu[B + ((rot + col) & 2047)] = rh;
      outu[B + ((rot + 512 + col) & 2047)] = rlo;
    }
  }
  bar_wait_poll<16>(grpb, 8u);

  // ---- steps 2..255: A = x_{t-1} hi/lo ----
  for (int t = 2; t < 256; ++t) {
    if constexpr (C > 0) {
      if ((t & (C - 1)) == 0) cache_acquire();   // kill stale ring lines
    }
    const size_t sr = (C > 0) ? (size_t)((t - 1) & (C - 1)) : (size_t)((t - 1) & 1);
    const size_t sw = (C > 0) ? (size_t)(t & (C - 1))       : (size_t)(t & 1);
    // tiled consumer base: tile (xg, ki), lane offset n16*32 + qo (contiguous 1KB/wave)
    const u16* xh = xpp + sr * 131072 + (size_t)xg * 16 * 512 + n16 * 32 + qo;
    const u16* xl = xh + 65536;
    short8 bufh[16], bufl[16];
    if constexpr (C > 0) {
#pragma unroll
      for (int ki = 0; ki < 16; ++ki) {
        bufh[ki] = *(const short8*)(xh + ki * 512);
        bufl[ki] = *(const short8*)(xl + ki * 512);
      }
    } else {
#pragma unroll
      for (int ki = 0; ki < 16; ++ki) {
        SC_LOAD(bufh[ki], xh + ki * 512);
        SC_LOAD(bufl[ki], xl + ki * 512);
      }
      WAIT8(0, bufh[0], bufh[1], bufh[2], bufh[3], bufh[4], bufh[5], bufh[6], bufh[7]);
      WAIT8(0, bufh[8], bufh[9], bufh[10], bufh[11], bufh[12], bufh[13], bufh[14], bufh[15]);
      WAIT8(0, bufl[0], bufl[1], bufl[2], bufl[3], bufl[4], bufl[5], bufl[6], bufl[7]);
      WAIT8(0, bufl[8], bufl[9], bufl[10], bufl[11], bufl[12], bufl[13], bufl[14], bufl[15]);
    }

    float4_ acc0 = {0.f, 0.f, 0.f, 0.f}, acc1 = acc0, acc2 = acc0;
#pragma unroll
    for (int ki = 0; ki < 16; ++ki) {
      const int ko = ki * 32 + qo;
      short8 b0h = *(const short8*)(wh_lds + (0 * 16 + n16) * 520 + ko);
      short8 b1h = *(const short8*)(wh_lds + (1 * 16 + n16) * 520 + ko);
      short8 b2h = *(const short8*)(wh_lds + (2 * 16 + n16) * 520 + ko);
      short8 b0l = *(const short8*)(wl_lds + (0 * 16 + n16) * 520 + ko);
      short8 b1l = *(const short8*)(wl_lds + (1 * 16 + n16) * 520 + ko);
      short8 b2l = *(const short8*)(wl_lds + (2 * 16 + n16) * 520 + ko);
      acc0 = MFMA(bufh[ki], b0h, acc0); acc0 = MFMA(bufl[ki], b0h, acc0); acc0 = MFMA(bufh[ki], b0l, acc0);
      acc1 = MFMA(bufh[ki], b1h, acc1); acc1 = MFMA(bufl[ki], b1h, acc1); acc1 = MFMA(bufh[ki], b1l, acc1);
      acc2 = MFMA(bufh[ki], b2h, acc2); acc2 = MFMA(bufl[ki], b2h, acc2); acc2 = MFMA(bufh[ki], b2l, acc2);
    }
    // compute x_t and store the ring FIRST (the only data other blocks need)
    for (int reg = 0; reg < 4; ++reg) {
      float ar = acc0[reg], az = acc1[reg], an = acc2[reg];
      float pr = __shfl_xor(ar, 8), pz = __shfl_xor(az, 8), pn = __shfl_xor(an, 8);
      float r  = sigm(ar + pr + blds[j8]);
      float zg = sigm(az + pz + blds[8 + j8]);
      float nn = tanhf(an + blds[16 + j8] + r * (pn + blds[24 + j8]));
      float xn = (1.f - zg) * nn + zg * x_own[reg];
      x_own[reg] = xn;
      if (act) {
        size_t po = xoff(orow0 + reg, col);
        u16 h, l; split2(xn, h, l);
        SC_STORE16(xpp + sw * 131072 + po, h);
        SC_STORE16(xpp + sw * 131072 + 65536 + po, l);
      }
    }
    if (t < 255) bar_arrive(mygrp);           // gen t
    if (act) {                                // seq stores overlap the wait
      for (int reg = 0; reg < 4; ++reg) {
        int row = orow0 + reg;
        float rl = fmaxf(x_own[reg], 0.f);
        u16 rh, rlo; split2(rl, rh, rlo);
        size_t B = ((size_t)row * 256 + (size_t)t) * 2048;
        u32 rot = (u32)(row & 15) * 128;
        outu[B + ((rot + col) & 2047)] = rh;
        outu[B + ((rot + 512 + col) & 2047)] = rlo;
      }
    }
    if (t < 255) bar_wait_poll<16>(grpb, (u32)t * 8u);
  }
}

// ---------------------------------------------------------------------------
// Kernel 2: persistent LSTM chain with fused FC. 256 blocks x 512 threads.
// 32 groups of 8. Early arrive (ring mode). h slot layout: TILED (see hoff).
// seq reads: rotated 256B/row. Weight LDS swizzle kept from round 11.
// ---------------------------------------------------------------------------
template<int C>
__global__ __launch_bounds__(512)
void lstm_fc_chain(const float* __restrict__ Wih, const float* __restrict__ Whh,
                   const float* __restrict__ bih, const float* __restrict__ bhh,
                   const float* __restrict__ fcW, const float* __restrict__ fcb,
                   u16* __restrict__ hpp, u16* outu, float* outf, u32* grpb) {
  __shared__ __align__(16) u16 whh_hi[16 * 1024];
  __shared__ __align__(16) u16 whh_lo[16 * 1024];
  __shared__ __align__(16) u16 wih_hi[16 * 512];
  __shared__ __align__(16) u16 wih_lo[16 * 512];
  __shared__ float glds[128][17];
  __shared__ float pglds[2][16][4][16];
  __shared__ float bclds[16];
  __shared__ float fclds[16];

  const int tid = threadIdx.x;
  const int s = blockIdx.x;
  const int colbase = s * 4;
  const int vt = s & 63, bq = s >> 6;
  const int vbase = vt * 16;
  u32* const mygrp = grpb + (size_t)(s >> 3) * 32;   // 32 groups of 8, 128B apart

  for (int idx = tid; idx < 16 * 1024; idx += 512) {
    int row = idx >> 10, k = idx & 1023;
    int gate = row >> 2, cc = row & 3;
    float w = Whh[(size_t)(gate * 1024 + colbase + cc) * 1024 + k];
    u16 h, l; split2(w, h, l);
    int ks = k ^ ((row & 7) << 3);            // bank swizzle (bijective per row)
    whh_hi[row * 1024 + ks] = h;
    whh_lo[row * 1024 + ks] = l;
  }
  for (int idx = tid; idx < 16 * 512; idx += 512) {
    int row = idx >> 9, k = idx & 511;
    int gate = row >> 2, cc = row & 3;
    float w = Wih[(size_t)(gate * 1024 + colbase + cc) * 512 + k];
    u16 h, l; split2(w, h, l);
    int ks = k ^ ((row & 7) << 3);
    wih_hi[row * 512 + ks] = h;
    wih_lo[row * 512 + ks] = l;
  }
  if (tid < 16) {
    int gate = tid >> 2, cc = tid & 3;
    int wcol = gate * 1024 + colbase + cc;
    bclds[tid] = bih[wcol] + bhh[wcol];
    fclds[tid] = fcb[vbase + tid];
  }
  __syncthreads();

  const int lane = tid & 63, wv = tid >> 6;
  const int n16 = lane & 15, q = lane >> 4;
  const int qo = q * 8;
  const int nsw = (n16 & 7) << 3;             // per-lane weight read swizzle
  const int arow = wv * 16 + n16;
  const int myrow = tid >> 2, mycol = tid & 3;
  const int fmt = wv & 1, fkq = wv >> 1;
  const int frow = bq * 32 + fmt * 16 + n16;
  const int fkbase = fkq * 256;
  const int fg = bq * 2 + fmt;                // frow >> 4 (tile row-group)

  short8 brh[8], brl[8];
  for (int i = 0; i < 8; ++i)
    frag_from_f32(fcW + (size_t)(vbase + n16) * 1024 + fkbase + i * 32 + qo,
                  brh[i], brl[i]);

  float c = 0.f;

  // t = 0: preacts are just biases; write h_0 into slot 0, arrive gen 1.
  {
    float pi = bclds[mycol], pg = bclds[8 + mycol], po = bclds[12 + mycol];
    c = sigm(pi) * tanhf(pg);
    float h = sigm(po) * tanhf(c);
    size_t off = hoff(myrow, colbase + mycol);
    u16 hh, hl; split2(h, hh, hl);
    SC_STORE16(hpp + off, hh);
    SC_STORE16(hpp + 131072 + off, hl);
  }
  bar_arrive(mygrp);   // gen 1

  for (int t = 1; t < 256; ++t) {
    const size_t sr = (C > 0) ? (size_t)((t - 1) & (C - 1)) : (size_t)((t - 1) & 1);
    const size_t sw = (C > 0) ? (size_t)(t & (C - 1))       : (size_t)(t & 1);

    // ---- input part FIRST (depends only on seq, not on h): hides the wait ----
    float4_ accI = {0.f, 0.f, 0.f, 0.f};
    {
      const u16* sqB = outu + ((size_t)arow * 256 + t) * 2048;
      const int rot = n16 * 128;              // (arow & 15) * 128
      for (int ki = 0; ki < 16; ++ki) {
        const int ko = ki * 32 + qo;
        const int kw = ko ^ nsw;
        short8 sh = *(const short8*)(sqB + ((rot + ko) & 2047));
        short8 sl = *(const short8*)(sqB + ((rot + 512 + ko) & 2047));
        short8 bh = *(const short8*)(wih_hi + n16 * 512 + kw);
        short8 bl = *(const short8*)(wih_lo + n16 * 512 + kw);
        accI = MFMA(sh, bh, accI); accI = MFMA(sl, bh, accI); accI = MFMA(sh, bl, accI);
      }
    }

    if constexpr (C > 0) {
      if ((t & (C - 1)) == 0) cache_acquire();   // kill stale ring lines
    }
    bar_wait_poll<32>(grpb, (u32)t * 8u);        // h_{t-1} now visible

    // tiled consumer base: tile (wv, jj), lane offset n16*32 + qo (1KB/wave load)
    const u16* ph = hpp + sr * 262144 + (size_t)wv * 32 * 512 + n16 * 32 + qo;
    const u16* pl = ph + 131072;

    // recurrent part, K=1024: 4 chunks of 8 jj; two independent acc chains
    float4_ accR0 = {0.f, 0.f, 0.f, 0.f}, accR1 = accR0;
    {
      short8 hb[2][8], lb[2][8];
      if constexpr (C > 0) {
#pragma unroll
        for (int j = 0; j < 8; ++j) {
          hb[0][j] = *(const short8*)(ph + j * 512);
          lb[0][j] = *(const short8*)(pl + j * 512);
        }
#pragma unroll
        for (int ch = 0; ch < 4; ++ch) {
          const int cur = ch & 1, nxt = cur ^ 1;
          if (ch < 3) {
#pragma unroll
            for (int j = 0; j < 8; ++j) {
              hb[nxt][j] = *(const short8*)(ph + ((ch + 1) * 8 + j) * 512);
              lb[nxt][j] = *(const short8*)(pl + ((ch + 1) * 8 + j) * 512);
            }
          }
          float4_& accR = (ch < 2) ? accR0 : accR1;
#pragma unroll
          for (int j = 0; j < 8; ++j) {
            const int ko = (ch * 8 + j) * 32 + qo;
            const int kw = ko ^ nsw;
            short8 bh = *(const short8*)(whh_hi + n16 * 1024 + kw);
            short8 bl = *(const short8*)(whh_lo + n16 * 1024 + kw);
            accR = MFMA(hb[cur][j], bh, accR);
            accR = MFMA(lb[cur][j], bh, accR);
            accR = MFMA(hb[cur][j], bl, accR);
          }
        }
      } else {
#pragma unroll
        for (int j = 0; j < 8; ++j) {
          SC_LOAD(hb[0][j], ph + j * 512);
          SC_LOAD(lb[0][j], pl + j * 512);
        }
#pragma unroll
        for (int ch = 0; ch < 4; ++ch) {
          const int cur = ch & 1, nxt = cur ^ 1;
          if (ch < 3) {
#pragma unroll
            for (int j = 0; j < 8; ++j) {
              SC_LOAD(hb[nxt][j], ph + ((ch + 1) * 8 + j) * 512);
              SC_LOAD(lb[nxt][j], pl + ((ch + 1) * 8 + j) * 512);
            }
            WAIT8(16, hb[cur][0], hb[cur][1], hb[cur][2], hb[cur][3],
                      hb[cur][4], hb[cur][5], hb[cur][6], hb[cur][7]);
            WAIT8(16, lb[cur][0], lb[cur][1], lb[cur][2], lb[cur][3],
                      lb[cur][4], lb[cur][5], lb[cur][6], lb[cur][7]);
          } else {
            WAIT8(0, hb[cur][0], hb[cur][1], hb[cur][2], hb[cur][3],
                     hb[cur][4], hb[cur][5], hb[cur][6], hb[cur][7]);
            WAIT8(0, lb[cur][0], lb[cur][1], lb[cur][2], lb[cur][3],
                     lb[cur][4], lb[cur][5], lb[cur][6], lb[cur][7]);
          }
          float4_& accR = (ch < 2) ? accR0 : accR1;
#pragma unroll
          for (int j = 0; j < 8; ++j) {
            const int ko = (ch * 8 + j) * 32 + qo;
            const int kw = ko ^ nsw;
            short8 bh = *(const short8*)(whh_hi + n16 * 1024 + kw);
            short8 bl = *(const short8*)(whh_lo + n16 * 1024 + kw);
            accR = MFMA(hb[cur][j], bh, accR);
            accR = MFMA(lb[cur][j], bh, accR);
            accR = MFMA(hb[cur][j], bl, accR);
          }
        }
      }
    }
    for (int reg = 0; reg < 4; ++reg)
      glds[wv * 16 + q * 4 + reg][n16] = accI[reg] + accR0[reg] + accR1[reg];
    __syncthreads();
    {
      float pi = glds[myrow][mycol]      + bclds[mycol];
      float pf = glds[myrow][4 + mycol]  + bclds[4 + mycol];
      float pg = glds[myrow][8 + mycol]  + bclds[8 + mycol];
      float po = glds[myrow][12 + mycol] + bclds[12 + mycol];
      c = sigm(pf) * c + sigm(pi) * tanhf(pg);
      float h = sigm(po) * tanhf(c);
      size_t off = hoff(myrow, colbase + mycol);
      u16 hh, hl; split2(h, hh, hl);
      SC_STORE16(hpp + sw * 262144 + off, hh);
      SC_STORE16(hpp + sw * 262144 + 131072 + off, hl);
    }

    // ring mode: arrive NOW -- the FC below is not consumed by other blocks.
    if constexpr (C > 0) bar_arrive(mygrp);   // gen t+1

    // fused FC: logits_{t-1} from h_{t-1} (slot sr), tiled reads
    {
      const u16* fh = hpp + sr * 262144 + ((size_t)fg * 32 + fkq * 8) * 512 + n16 * 32 + qo;
      const u16* fl = fh + 131072;
      short8 fhb[8], flb[8];
      if constexpr (C > 0) {
#pragma unroll
        for (int i = 0; i < 8; ++i) {
          fhb[i] = *(const short8*)(fh + i * 512);
          flb[i] = *(const short8*)(fl + i * 512);
        }
      } else {
#pragma unroll
        for (int i = 0; i < 8; ++i) {
          SC_LOAD(fhb[i], fh + i * 512);
          SC_LOAD(flb[i], fl + i * 512);
        }
        WAIT8(0, fhb[0], fhb[1], fhb[2], fhb[3], fhb[4], fhb[5], fhb[6], fhb[7]);
        WAIT8(0, flb[0], flb[1], flb[2], flb[3], flb[4], flb[5], flb[6], flb[7]);
      }
      float4_ lacc = {0.f, 0.f, 0.f, 0.f};
#pragma unroll
      for (int i = 0; i < 8; ++i) {
        lacc = MFMA(fhb[i], brh[i], lacc);
        lacc = MFMA(flb[i], brh[i], lacc);
        lacc = MFMA(fhb[i], brl[i], lacc);
      }
      for (int reg = 0; reg < 4; ++reg)
        pglds[fmt][q * 4 + reg][fkq][n16] = lacc[reg];
      __syncthreads();
      int trow = tid >> 4, tcol = tid & 15;
      float lsum = pglds[trow >> 4][trow & 15][0][tcol] + pglds[trow >> 4][trow & 15][1][tcol] +
                   pglds[trow >> 4][trow & 15][2][tcol] + pglds[trow >> 4][trow & 15][3][tcol] +
                   fclds[tcol];
      outf[((size_t)(bq * 32 + trow) * 256 + (t - 1)) * 1024 + vbase + tcol] = lsum;
    }

    if constexpr (C == 0) bar_arrive(mygrp);  // legacy order for 2-slot mode
  }

  // epilogue: logits_255 from h_255
  {
    bar_wait_poll<32>(grpb, 256u * 8u);
    if constexpr (C > 0) cache_acquire();
    const size_t sl = (C > 0) ? (size_t)(255 & (C - 1)) : (size_t)1;
    const u16* fh = hpp + sl * 262144 + ((size_t)fg * 32 + fkq * 8) * 512 + n16 * 32 + qo;
    const u16* fl = fh + 131072;
    short8 fhb[8], flb[8];
    if constexpr (C > 0) {
#pragma unroll
      for (int i = 0; i < 8; ++i) {
        fhb[i] = *(const short8*)(fh + i * 512);
        flb[i] = *(const short8*)(fl + i * 512);
      }
    } else {
#pragma unroll
      for (int i = 0; i < 8; ++i) {
        SC_LOAD(fhb[i], fh + i * 512);
        SC_LOAD(flb[i], fl + i * 512);
      }
      WAIT8(0, fhb[0], fhb[1], fhb[2], fhb[3], fhb[4], fhb[5], fhb[6], fhb[7]);
      WAIT8(0, flb[0], flb[1], flb[2], flb[3], flb[4], flb[5], flb[6], flb[7]);
    }
    float4_ lacc = {0.f, 0.f, 0.f, 0.f};
#pragma unroll
    for (int i = 0; i < 8; ++i) {
      lacc = MFMA(fhb[i], brh[i], lacc);
      lacc = MFMA(flb[i], brh[i], lacc);
      lacc = MFMA(fhb[i], brl[i], lacc);
    }
    for (int reg = 0; reg < 4; ++reg)
      pglds[fmt][q * 4 + reg][fkq][n16] = lacc[reg];
    __syncthreads();
    int trow = tid >> 4, tcol = tid & 15;
    float lsum = pglds[trow >> 4][trow & 15][0][tcol] + pglds[trow >> 4][trow & 15][1][tcol] +
                 pglds[trow >> 4][trow & 15][2][tcol] + pglds[trow >> 4][trow & 15][3][tcol] +
                 fclds[tcol];
    outf[((size_t)(bq * 32 + trow) * 256 + 255) * 1024 + vbase + tcol] = lsum;
  }
}

// ---------------------------------------------------------------------------
extern "C" void kernel_launch(void* const* d_in, const int* in_sizes, int n_in,
                              void* d_out, int out_size, void* d_ws, size_t ws_size,
                              hipStream_t stream) {
  (void)in_sizes; (void)n_in; (void)out_size;
  const float* z    = (const float*)d_in[0];
  const float* gWih = (const float*)d_in[2];
  const float* gWhh = (const float*)d_in[3];
  const float* gbih = (const float*)d_in[4];
  const float* gbhh = (const float*)d_in[5];
  const float* lWih = (const float*)d_in[6];
  const float* lWhh = (const float*)d_in[7];
  const float* lbih = (const float*)d_in[8];
  const float* lbhh = (const float*)d_in[9];
  const float* fcW  = (const float*)d_in[10];
  const float* fcb  = (const float*)d_in[11];

  const size_t XS = 262144;   // x slot bytes (2 planes x 128x512 bf16, tiled)
  const size_t HS = 524288;   // h slot bytes (2 planes x 128x1024 bf16, tiled)
  const size_t BAR = 8192;    // barrier region: 32 LSTM + 16 GRU group lines

  char* w = (char*)d_ws;
  u32* grpL = (u32*)(w + 512);    // 32 x 128B LSTM group lines
  u32* grpG = (u32*)(w + 4608);   // 16 x 128B GRU group lines

  hipMemsetAsync(d_ws, 0, BAR, stream);   // zero all barrier counters

#define LAUNCH(CG, CL, XSLOTS)                                                     \
  do {                                                                             \
    u16* xpp = (u16*)(w + BAR);                                                    \
    u16* hpp = (u16*)(w + BAR + (size_t)(XSLOTS) * XS);                            \
    gru_chain<CG><<<128, 256, 0, stream>>>(z, gWih, gWhh, gbih, gbhh,              \
                                           (u16*)d_out, xpp, grpG);                \
    lstm_fc_chain<CL><<<256, 512, 0, stream>>>(lWih, lWhh, lbih, lbhh, fcW, fcb,   \
                                               hpp, (u16*)d_out, (float*)d_out,    \
                                               grpL);                              \
  } while (0)

  if      (ws_size >= BAR + 64 * XS + 128 * HS) LAUNCH(64, 128, 64);  // 83.9 MB
  else if (ws_size >= BAR + 32 * XS +  64 * HS) LAUNCH(32,  64, 32);  // 41.9 MB
  else if (ws_size >= BAR + 16 * XS +  32 * HS) LAUNCH(16,  32, 16);  // 21.0 MB
  else if (ws_size >= BAR +  8 * XS +  16 * HS) LAUNCH( 8,  16,  8);  // 10.5 MB
  else if (ws_size >= BAR +  2 * XS +   8 * HS) LAUNCH( 0,   8,  2);  //  4.7 MB (guaranteed)
  else if (ws_size >= BAR +  2 * XS +   2 * HS) LAUNCH( 0,   0,  2);  //  1.5 MB fallback
  else return;

#undef LAUNCH
}